// Round 12
// baseline (223.636 us; speedup 1.0000x reference)
//
#include <hip/hip_runtime.h>
#include <hip/hip_bf16.h>
#include <stdint.h>

// RNNPool on MI355X: B=16, S=4096, E=512, window=8.
// Round 12: rec drops the LDS weight ring (r11 ledger: ring = 1MB/step LDS
// pass-through + per-iter lgkm/vmcnt serialization). Weights now stream
// global(L2)->VGPR through an explicit 3-set register pipeline (named
// scalars, guarded rotation, full unroll -- the allocator-proof idiom from
// r11; 512-thr block keeps the 256-VGPR budget). No inline-asm waits: no
// shared-buffer WAR hazard remains, compiler's counted waitcnt is optimal.
// h: fp16 ping-pong in LDS, ONE barrier per step.
// fp16 everywhere (r7/r9/r10/r11: absmax 0.0039 << 0.02).

#define E_DIM 512
#define KSIZE 8
#define R_WIN 32           // windows per block
#define NBLK  256

typedef __attribute__((ext_vector_type(8))) _Float16       f16x8;   // MFMA A/B frag
typedef __attribute__((ext_vector_type(4))) float          f32x4;   // MFMA C/D frag
typedef __attribute__((ext_vector_type(4))) float          fv4;
typedef __attribute__((ext_vector_type(4))) unsigned short u16x4;
typedef __attribute__((ext_vector_type(8))) unsigned short u16x8;

__device__ __forceinline__ unsigned short f2h(float f) {
  return __builtin_bit_cast(unsigned short, (_Float16)f);
}
__device__ __forceinline__ float h2f(unsigned short u) {
  return (float)__builtin_bit_cast(_Float16, u);
}
__device__ __forceinline__ float tanh_fast(float v) {
  return 1.0f - 2.0f / (1.0f + __expf(2.0f * v));   // exact saturation, 1 v_exp
}
// LDS XOR-swizzle key (function of row only: write/read sides agree).
__device__ __forceinline__ int swz(int row) { return (row ^ (row >> 1)) & 7; }

// ---------------------------------------------------------------------------
// Pack W_ih / W_hh (fp32) into fp16 fragment-major, K-SLICE-MAJOR:
//   ushort idx = ((m*16 + s)*32 + n)*512 + l*8
//   (lane l holds W[n*16 + (l&15)][s*32 + (l>>4)*8 + j])
// bias[n] = b_ih[n] + b_hh[n] (fp32).
// ---------------------------------------------------------------------------
__global__ void pack_kernel(const float* __restrict__ Wih, const float* __restrict__ Whh,
                            const float* __restrict__ bih, const float* __restrict__ bhh,
                            unsigned short* __restrict__ wpack, float* __restrict__ bias) {
  int tid = blockIdx.x * 256 + threadIdx.x;          // 65536 threads total
  int l = tid & 63;
  int s = (tid >> 6) & 15;
  int n = (tid >> 10) & 31;
  int m = tid >> 15;
  const float* W = m ? Whh : Wih;
  int row = n * 16 + (l & 15);
  int k0  = s * 32 + (l >> 4) * 8;
  const float* src = W + row * E_DIM + k0;
  u16x8 u;
  #pragma unroll
  for (int j = 0; j < 8; ++j) u[j] = f2h(src[j]);
  size_t dst = (((size_t)m * 16 + s) * 32 + n) * 512 + (size_t)l * 8;
  *reinterpret_cast<u16x8*>(wpack + dst) = u;
  if (tid < E_DIM) bias[tid] = bih[tid] + bhh[tid];
}

// PRE fragment layout (fp16): frag id = ((bt*2 + mt)*32 + nt), bt = b*8+t.
#define PRE_FRAG(bt, mt, nt) ((((size_t)(bt) * 2 + (mt)) * 32 + (nt)) * 256)

// ---------------------------------------------------------------------------
// Phase 1: PRE = fp16(x_t @ W_ih^T + bias). Grid 2048, 512 thr (8 waves x 4 N).
// ---------------------------------------------------------------------------
__global__ __launch_bounds__(512, 4)
void pre_kernel(const float* __restrict__ x,
                const unsigned short* __restrict__ wpack,
                const float* __restrict__ bias,
                unsigned short* __restrict__ prep) {
  __shared__ unsigned short x_lds[R_WIN * E_DIM];   // 32 KB (fp16)

  const int bt   = blockIdx.x;
  const int b    = bt >> 3;
  const int t    = bt & 7;
  const int w0   = b * R_WIN;
  const int tid  = threadIdx.x;
  const int lane = tid & 63;
  const int wid  = tid >> 6;          // 0..7
  const int l15  = lane & 15;
  const int a5   = lane >> 4;
  const int nt0  = wid * 4;

  float bias_r[4];
  #pragma unroll
  for (int n = 0; n < 4; ++n) bias_r[n] = bias[(nt0 + n) * 16 + l15];

  // stage x: fp32 global (nontemporal) -> fp16 swizzled LDS
  {
    const int srow = tid >> 4;
    const int sc4  = tid & 15;
    const fv4* src4 = reinterpret_cast<const fv4*>(
        x + (size_t)((w0 + srow) * KSIZE + t) * E_DIM);
    #pragma unroll
    for (int j = 0; j < 8; ++j) {
      fv4 v = __builtin_nontemporal_load(&src4[sc4 + 16 * j]);
      int col  = (sc4 + 16 * j) * 4;
      int idx  = srow * E_DIM + (((col >> 3) ^ swz(srow)) << 3) + (col & 7);
      u16x4 u;
      u[0] = f2h(v.x); u[1] = f2h(v.y); u[2] = f2h(v.z); u[3] = f2h(v.w);
      *reinterpret_cast<u16x4*>(&x_lds[idx]) = u;
    }
  }
  __syncthreads();

  f32x4 acc[2][4];
  #pragma unroll
  for (int mt = 0; mt < 2; ++mt)
    #pragma unroll
    for (int n = 0; n < 4; ++n) acc[mt][n] = (f32x4){0.f, 0.f, 0.f, 0.f};

  #pragma unroll
  for (int s = 0; s < 16; ++s) {
    int u0 = s * 4 + a5;
    int ia = l15 * E_DIM + ((u0 ^ swz(l15)) << 3);
    f16x8 A0 = *reinterpret_cast<const f16x8*>(&x_lds[ia]);
    f16x8 A1 = *reinterpret_cast<const f16x8*>(&x_lds[ia + 16 * E_DIM]);
    const unsigned short* wsl = wpack + ((size_t)s * 32 + nt0) * 512 + lane * 8;
    #pragma unroll
    for (int n = 0; n < 4; ++n) {
      f16x8 Bf = *reinterpret_cast<const f16x8*>(wsl + n * 512);
      acc[0][n] = __builtin_amdgcn_mfma_f32_16x16x32_f16(A0, Bf, acc[0][n], 0, 0, 0);
      acc[1][n] = __builtin_amdgcn_mfma_f32_16x16x32_f16(A1, Bf, acc[1][n], 0, 0, 0);
    }
  }

  // store fragment-major fp16, nontemporal
  #pragma unroll
  for (int mt = 0; mt < 2; ++mt)
    #pragma unroll
    for (int n = 0; n < 4; ++n) {
      u16x4 v;
      #pragma unroll
      for (int r = 0; r < 4; ++r) v[r] = f2h(acc[mt][n][r] + bias_r[n]);
      __builtin_nontemporal_store(v,
          reinterpret_cast<u16x4*>(&prep[PRE_FRAG(bt, mt, nt0 + n) + lane * 4]));
    }
}

// ---------------------------------------------------------------------------
// Phase 2: recurrence. Grid 256 (1 block/CU), 512 thr = 8 waves.
// Wave wid owns N-tiles nt0=wid*4..+3 for BOTH M-tiles.
// Weights: global(L2)->VGPR, 3-set register pipeline (A consume / B ready /
// C landing), plain C++ loads, compiler-managed waitcnt.
// h: fp16 ping-pong (2x32KB) -> ONE barrier per step. LDS total: 64 KB.
// ---------------------------------------------------------------------------
__global__ __launch_bounds__(512, 1)
void rec_kernel(const unsigned short* __restrict__ prep,
                const unsigned short* __restrict__ wpack,
                float* __restrict__ out) {
  __shared__ unsigned short h_buf[2][R_WIN * E_DIM];  // 2 x 32 KB fp16

  const int b    = blockIdx.x;
  const int w0   = b * R_WIN;
  const int tid  = threadIdx.x;
  const int lane = tid & 63;
  const int wid  = tid >> 6;            // 0..7
  const int l15  = lane & 15;
  const int a5   = lane >> 4;
  const int nt0  = wid * 4;

  // W_hh fragment base for this wave/lane (k-slice-major pack):
  //   frag(s, n) at wH + s*16384 + n*512   (ushort units)
  const unsigned short* wH = wpack + 262144 + (size_t)nt0 * 512 + (size_t)lane * 8;
  #define WLOAD(s, n) (*reinterpret_cast<const f16x8*>(wH + (size_t)(s) * 16384 + (n) * 512))

  // ---- t = 0: h[0] = tanh(PRE_0) ----
  #pragma unroll
  for (int mt = 0; mt < 2; ++mt)
    #pragma unroll
    for (int n = 0; n < 4; ++n) {
      u16x4 p = __builtin_nontemporal_load(reinterpret_cast<const u16x4*>(
          &prep[PRE_FRAG(b * 8 + 0, mt, nt0 + n) + lane * 4]));
      int ncol = (nt0 + n) * 16 + l15;
      int ub = ncol >> 3, co = ncol & 7;
      #pragma unroll
      for (int r = 0; r < 4; ++r) {
        int row = mt * 16 + a5 * 4 + r;
        int idx = row * E_DIM + ((ub ^ swz(row)) << 3) + co;
        h_buf[0][idx] = f2h(tanh_fast(h2f(p[r])));
      }
    }

  // prefetch PRE_1
  u16x4 nxt[2][4];
  #pragma unroll
  for (int mt = 0; mt < 2; ++mt)
    #pragma unroll
    for (int n = 0; n < 4; ++n)
      nxt[mt][n] = __builtin_nontemporal_load(reinterpret_cast<const u16x4*>(
          &prep[PRE_FRAG(b * 8 + 1, mt, nt0 + n) + lane * 4]));

  __syncthreads();   // h[0] visible; drains all VMEM (incl. PRE_1)

  int cur = 0;
  for (int t = 1; t < KSIZE; ++t) {
    f32x4 acc[2][4];
    #pragma unroll
    for (int mt = 0; mt < 2; ++mt)
      #pragma unroll
      for (int n = 0; n < 4; ++n) {
        #pragma unroll
        for (int r = 0; r < 4; ++r) acc[mt][n][r] = h2f(nxt[mt][n][r]);
      }

    // ---- prologue: weights slice 0 -> A set, slice 1 -> B set; h slice 0 ----
    f16x8 Wa0 = WLOAD(0, 0), Wa1 = WLOAD(0, 1), Wa2 = WLOAD(0, 2), Wa3 = WLOAD(0, 3);
    f16x8 Wb0 = WLOAD(1, 0), Wb1 = WLOAD(1, 1), Wb2 = WLOAD(1, 2), Wb3 = WLOAD(1, 3);
    f16x8 Ha0, Ha1, Hb0, Hb1;
    {
      int ia0 = l15 * E_DIM + ((a5 ^ swz(l15)) << 3);
      int ia1 = (16 + l15) * E_DIM + ((a5 ^ swz(16 + l15)) << 3);
      Ha0 = *reinterpret_cast<const f16x8*>(&h_buf[cur][ia0]);
      Ha1 = *reinterpret_cast<const f16x8*>(&h_buf[cur][ia1]);
    }

    // ---- s-loop: MFMA slice s (A sets) while loading s+2 (C) & reading s+1 ----
    #pragma unroll
    for (int s = 0; s < 16; ++s) {
      f16x8 Wc0, Wc1, Wc2, Wc3;
      if (s + 2 < 16) {
        Wc0 = WLOAD(s + 2, 0); Wc1 = WLOAD(s + 2, 1);
        Wc2 = WLOAD(s + 2, 2); Wc3 = WLOAD(s + 2, 3);
      }
      if (s + 1 < 16) {
        int u0  = (s + 1) * 4 + a5;
        int ia0 = l15 * E_DIM + ((u0 ^ swz(l15)) << 3);
        int ia1 = (16 + l15) * E_DIM + ((u0 ^ swz(16 + l15)) << 3);
        Hb0 = *reinterpret_cast<const f16x8*>(&h_buf[cur][ia0]);
        Hb1 = *reinterpret_cast<const f16x8*>(&h_buf[cur][ia1]);
      }
      acc[0][0] = __builtin_amdgcn_mfma_f32_16x16x32_f16(Ha0, Wa0, acc[0][0], 0, 0, 0);
      acc[1][0] = __builtin_amdgcn_mfma_f32_16x16x32_f16(Ha1, Wa0, acc[1][0], 0, 0, 0);
      acc[0][1] = __builtin_amdgcn_mfma_f32_16x16x32_f16(Ha0, Wa1, acc[0][1], 0, 0, 0);
      acc[1][1] = __builtin_amdgcn_mfma_f32_16x16x32_f16(Ha1, Wa1, acc[1][1], 0, 0, 0);
      acc[0][2] = __builtin_amdgcn_mfma_f32_16x16x32_f16(Ha0, Wa2, acc[0][2], 0, 0, 0);
      acc[1][2] = __builtin_amdgcn_mfma_f32_16x16x32_f16(Ha1, Wa2, acc[1][2], 0, 0, 0);
      acc[0][3] = __builtin_amdgcn_mfma_f32_16x16x32_f16(Ha0, Wa3, acc[0][3], 0, 0, 0);
      acc[1][3] = __builtin_amdgcn_mfma_f32_16x16x32_f16(Ha1, Wa3, acc[1][3], 0, 0, 0);
      if (s + 1 < 16) {                       // rotate (SSA-renamed by unroll)
        Wa0 = Wb0; Wa1 = Wb1; Wa2 = Wb2; Wa3 = Wb3;
        Ha0 = Hb0; Ha1 = Hb1;
      }
      if (s + 2 < 16) {
        Wb0 = Wc0; Wb1 = Wc1; Wb2 = Wc2; Wb3 = Wc3;
      }
    }

    if (t == KSIZE - 1) {
      #pragma unroll
      for (int mt = 0; mt < 2; ++mt)
        #pragma unroll
        for (int n = 0; n < 4; ++n) {
          int ncol = (nt0 + n) * 16 + l15;
          #pragma unroll
          for (int r = 0; r < 4; ++r) {
            int row = mt * 16 + a5 * 4 + r;
            out[(size_t)(w0 + row) * E_DIM + ncol] = tanh_fast(acc[mt][n][r]);
          }
        }
    } else {
      // issue next step's PRE now: HBM latency hides under the epilogue;
      // the step barrier drains it.
      #pragma unroll
      for (int mt = 0; mt < 2; ++mt)
        #pragma unroll
        for (int n = 0; n < 4; ++n)
          nxt[mt][n] = __builtin_nontemporal_load(reinterpret_cast<const u16x4*>(
              &prep[PRE_FRAG(b * 8 + t + 1, mt, nt0 + n) + lane * 4]));

      // write h[cur^1]; waves may still read h[cur] -- different buffer.
      int nb = cur ^ 1;
      #pragma unroll
      for (int mt = 0; mt < 2; ++mt)
        #pragma unroll
        for (int n = 0; n < 4; ++n) {
          int ncol = (nt0 + n) * 16 + l15;
          int ub = ncol >> 3, co = ncol & 7;
          #pragma unroll
          for (int r = 0; r < 4; ++r) {
            int row = mt * 16 + a5 * 4 + r;
            int idx = row * E_DIM + ((ub ^ swz(row)) << 3) + co;
            h_buf[nb][idx] = f2h(tanh_fast(acc[mt][n][r]));
          }
        }
      __syncthreads();   // ONE barrier per step: h[nb] visible to all
      cur = nb;
    }
  }
  #undef WLOAD
}

// ---------------------------------------------------------------------------
// Fallback (fused, fp16) for small ws_size. k-slice-major wpack.
// ---------------------------------------------------------------------------
__global__ __launch_bounds__(512, 1)
void rnnpool_fused(const float* __restrict__ x,
                   const unsigned short* __restrict__ wpack,
                   const float* __restrict__ bias,
                   float* __restrict__ out) {
  __shared__ unsigned short x_lds[R_WIN * E_DIM];
  __shared__ unsigned short h_lds[R_WIN * E_DIM];

  const int tid  = threadIdx.x;
  const int lane = tid & 63;
  const int wid  = tid >> 6;
  const int w0   = blockIdx.x * R_WIN;
  const int l15 = lane & 15;
  const int a5  = lane >> 4;
  const int nt0 = wid * 4;

  float bias_r[4];
  #pragma unroll
  for (int n = 0; n < 4; ++n) bias_r[n] = bias[(nt0 + n) * 16 + l15];

  const int srow = tid >> 4;
  const int sc4  = tid & 15;

  for (int t = 0; t < KSIZE; ++t) {
    {
      const fv4* src4 = reinterpret_cast<const fv4*>(
          x + (size_t)((w0 + srow) * KSIZE + t) * E_DIM);
      #pragma unroll
      for (int j = 0; j < 8; ++j) {
        fv4 v = src4[sc4 + 16 * j];
        int col  = (sc4 + 16 * j) * 4;
        int idx  = srow * E_DIM + (((col >> 3) ^ swz(srow)) << 3) + (col & 7);
        u16x4 u;
        u[0] = f2h(v.x); u[1] = f2h(v.y); u[2] = f2h(v.z); u[3] = f2h(v.w);
        *reinterpret_cast<u16x4*>(&x_lds[idx]) = u;
      }
    }
    __syncthreads();

    f32x4 acc[2][4];
    #pragma unroll
    for (int mt = 0; mt < 2; ++mt)
      #pragma unroll
      for (int n = 0; n < 4; ++n) acc[mt][n] = (f32x4){0.f, 0.f, 0.f, 0.f};

    #pragma unroll
    for (int s = 0; s < 16; ++s) {
      int u0 = s * 4 + a5;
      int ia = l15 * E_DIM + ((u0 ^ swz(l15)) << 3);
      f16x8 A0 = *reinterpret_cast<const f16x8*>(&x_lds[ia]);
      f16x8 A1 = *reinterpret_cast<const f16x8*>(&x_lds[ia + 16 * E_DIM]);
      const unsigned short* wsl = wpack + ((size_t)s * 32 + nt0) * 512 + lane * 8;
      #pragma unroll
      for (int n = 0; n < 4; ++n) {
        f16x8 Bf = *reinterpret_cast<const f16x8*>(wsl + n * 512);
        acc[0][n] = __builtin_amdgcn_mfma_f32_16x16x32_f16(A0, Bf, acc[0][n], 0, 0, 0);
        acc[1][n] = __builtin_amdgcn_mfma_f32_16x16x32_f16(A1, Bf, acc[1][n], 0, 0, 0);
      }
    }

    if (t > 0) {
      #pragma unroll
      for (int s = 0; s < 16; ++s) {
        int u0 = s * 4 + a5;
        int ia = l15 * E_DIM + ((u0 ^ swz(l15)) << 3);
        f16x8 H0 = *reinterpret_cast<const f16x8*>(&h_lds[ia]);
        f16x8 H1 = *reinterpret_cast<const f16x8*>(&h_lds[ia + 16 * E_DIM]);
        const unsigned short* wsl = wpack + ((size_t)(16 + s) * 32 + nt0) * 512 + lane * 8;
        #pragma unroll
        for (int n = 0; n < 4; ++n) {
          f16x8 Bf = *reinterpret_cast<const f16x8*>(wsl + n * 512);
          acc[0][n] = __builtin_amdgcn_mfma_f32_16x16x32_f16(H0, Bf, acc[0][n], 0, 0, 0);
          acc[1][n] = __builtin_amdgcn_mfma_f32_16x16x32_f16(H1, Bf, acc[1][n], 0, 0, 0);
        }
      }
    }
    __syncthreads();

    if (t == KSIZE - 1) {
      #pragma unroll
      for (int mt = 0; mt < 2; ++mt)
        #pragma unroll
        for (int n = 0; n < 4; ++n) {
          int ncol = (nt0 + n) * 16 + l15;
          #pragma unroll
          for (int r = 0; r < 4; ++r) {
            int row = mt * 16 + a5 * 4 + r;
            out[(size_t)(w0 + row) * E_DIM + ncol] = tanh_fast(acc[mt][n][r] + bias_r[n]);
          }
        }
    } else {
      #pragma unroll
      for (int mt = 0; mt < 2; ++mt)
        #pragma unroll
        for (int n = 0; n < 4; ++n) {
          int ncol = (nt0 + n) * 16 + l15;
          int ub = ncol >> 3, co = ncol & 7;
          #pragma unroll
          for (int r = 0; r < 4; ++r) {
            int row = mt * 16 + a5 * 4 + r;
            int idx = row * E_DIM + ((ub ^ swz(row)) << 3) + co;
            h_lds[idx] = f2h(tanh_fast(acc[mt][n][r] + bias_r[n]));
          }
        }
      __syncthreads();
    }
  }
}

extern "C" void kernel_launch(void* const* d_in, const int* in_sizes, int n_in,
                              void* d_out, int out_size, void* d_ws, size_t ws_size,
                              hipStream_t stream) {
  const float* x   = (const float*)d_in[0];
  const float* Wih = (const float*)d_in[1];
  const float* Whh = (const float*)d_in[2];
  const float* bih = (const float*)d_in[3];
  const float* bhh = (const float*)d_in[4];
  float* out = (float*)d_out;

  const size_t PRE_BYTES  = (size_t)33554432 * 2;      // 67.1 MB (fp16)
  const size_t WPK_BYTES  = (size_t)524288 * 2;        // 1 MB
  const size_t NEED       = PRE_BYTES + WPK_BYTES + 4096;

  if (ws_size >= NEED) {
    unsigned short* prep  = (unsigned short*)d_ws;
    unsigned short* wpack = (unsigned short*)((char*)d_ws + PRE_BYTES);
    float*          bias  = (float*)((char*)d_ws + PRE_BYTES + WPK_BYTES);
    pack_kernel<<<256, 256, 0, stream>>>(Wih, Whh, bih, bhh, wpack, bias);
    pre_kernel<<<2048, 512, 0, stream>>>(x, wpack, bias, prep);
    rec_kernel<<<NBLK, 512, 0, stream>>>(prep, wpack, out);
  } else {
    unsigned short* wpack = (unsigned short*)d_ws;
    float*          bias  = (float*)((char*)d_ws + WPK_BYTES);
    pack_kernel<<<256, 256, 0, stream>>>(Wih, Whh, bih, bhh, wpack, bias);
    rnnpool_fused<<<NBLK, 512, 0, stream>>>(x, wpack, bias, out);
  }
}

// Round 13
// 152.751 us; speedup vs baseline: 1.4641x; 1.4641x over previous
//
#include <hip/hip_runtime.h>
#include <hip/hip_bf16.h>
#include <stdint.h>

// RNNPool on MI355X: B=16, S=4096, E=512, window=8.
// Round 13: rec reverted to r11 verbatim (best proven: 91us; DMA weight ring,
// 2-deep, counted vmcnt, h ping-pong, 512thr/128VGPR). r12's global->VGPR
// pipeline spilled to scratch (FETCH 275MB + WRITE 103MB signature).
// pre rebuilt: 1024 blocks x 64 windows -> halves W_ih L2 re-fetch (1GB->0.5GB)
// and doubles MFMA:load ILP (16 MFMA : 8 loads per slice); 2 blocks/CU.
// fp16 everywhere (absmax 0.0039 << 0.02, stable since r7).

#define E_DIM 512
#define KSIZE 8
#define R_WIN 32           // windows per rec block
#define R_PRE 64           // windows per pre block
#define NBLK  256

typedef __attribute__((ext_vector_type(8))) _Float16       f16x8;   // MFMA A/B frag
typedef __attribute__((ext_vector_type(4))) float          f32x4;   // MFMA C/D frag
typedef __attribute__((ext_vector_type(4))) float          fv4;
typedef __attribute__((ext_vector_type(4))) unsigned short u16x4;
typedef __attribute__((ext_vector_type(8))) unsigned short u16x8;

typedef __attribute__((address_space(1))) const uint32_t glb_u32;
typedef __attribute__((address_space(3))) uint32_t       lds_u32;

__device__ __forceinline__ unsigned short f2h(float f) {
  return __builtin_bit_cast(unsigned short, (_Float16)f);
}
__device__ __forceinline__ float h2f(unsigned short u) {
  return (float)__builtin_bit_cast(_Float16, u);
}
__device__ __forceinline__ float tanh_fast(float v) {
  return 1.0f - 2.0f / (1.0f + __expf(2.0f * v));   // exact saturation, 1 v_exp
}
// LDS XOR-swizzle key (function of row only: write/read sides agree).
__device__ __forceinline__ int swz(int row) { return (row ^ (row >> 1)) & 7; }

// ---------------------------------------------------------------------------
// Pack W_ih / W_hh (fp32) into fp16 fragment-major, K-SLICE-MAJOR:
//   ushort idx = ((m*16 + s)*32 + n)*512 + l*8
//   (lane l holds W[n*16 + (l&15)][s*32 + (l>>4)*8 + j])
// bias[n] = b_ih[n] + b_hh[n] (fp32).
// ---------------------------------------------------------------------------
__global__ void pack_kernel(const float* __restrict__ Wih, const float* __restrict__ Whh,
                            const float* __restrict__ bih, const float* __restrict__ bhh,
                            unsigned short* __restrict__ wpack, float* __restrict__ bias) {
  int tid = blockIdx.x * 256 + threadIdx.x;          // 65536 threads total
  int l = tid & 63;
  int s = (tid >> 6) & 15;
  int n = (tid >> 10) & 31;
  int m = tid >> 15;
  const float* W = m ? Whh : Wih;
  int row = n * 16 + (l & 15);
  int k0  = s * 32 + (l >> 4) * 8;
  const float* src = W + row * E_DIM + k0;
  u16x8 u;
  #pragma unroll
  for (int j = 0; j < 8; ++j) u[j] = f2h(src[j]);
  size_t dst = (((size_t)m * 16 + s) * 32 + n) * 512 + (size_t)l * 8;
  *reinterpret_cast<u16x8*>(wpack + dst) = u;
  if (tid < E_DIM) bias[tid] = bih[tid] + bhh[tid];
}

// PRE fragment layout (fp16): frag id = ((bt*2 + mt)*32 + nt), bt = rb*8+t,
// rb = rec block in [0,256).
#define PRE_FRAG(bt, mt, nt) ((((size_t)(bt) * 2 + (mt)) * 32 + (nt)) * 256)

// ---------------------------------------------------------------------------
// Phase 1: PRE = fp16(x_t @ W_ih^T + bias). Grid 1024 (=128 groups x 8 t),
// 64 windows/block, 512 thr = 8 waves, wave = M4 x N4 (16 MFMA : 8 loads).
// 64KB LDS -> 2 blocks/CU. Weight L2 traffic halved vs 2048-block version.
// ---------------------------------------------------------------------------
__global__ __launch_bounds__(512, 2)
void pre_kernel(const float* __restrict__ x,
                const unsigned short* __restrict__ wpack,
                const float* __restrict__ bias,
                unsigned short* __restrict__ prep) {
  __shared__ unsigned short x_lds[R_PRE * E_DIM];   // 64 KB (fp16)

  const int bt   = blockIdx.x;          // 0..1023
  const int b    = bt >> 3;             // 0..127
  const int t    = bt & 7;
  const int w0   = b * R_PRE;
  const int tid  = threadIdx.x;
  const int lane = tid & 63;
  const int wid  = tid >> 6;            // 0..7
  const int l15  = lane & 15;
  const int a5   = lane >> 4;
  const int nt0  = wid * 4;

  float bias_r[4];
  #pragma unroll
  for (int n = 0; n < 4; ++n) bias_r[n] = bias[(nt0 + n) * 16 + l15];

  // stage x: 64 rows fp32 global (nontemporal) -> fp16 swizzled LDS
  {
    const int srow = tid >> 3;          // 0..63
    const int sc   = tid & 7;           // float4 column base
    const fv4* src4 = reinterpret_cast<const fv4*>(
        x + (size_t)((w0 + srow) * KSIZE + t) * E_DIM);
    #pragma unroll
    for (int j = 0; j < 16; ++j) {
      fv4 v = __builtin_nontemporal_load(&src4[sc + 8 * j]);
      int col  = (sc + 8 * j) * 4;
      int idx  = srow * E_DIM + (((col >> 3) ^ swz(srow)) << 3) + (col & 7);
      u16x4 u;
      u[0] = f2h(v.x); u[1] = f2h(v.y); u[2] = f2h(v.z); u[3] = f2h(v.w);
      *reinterpret_cast<u16x4*>(&x_lds[idx]) = u;
    }
  }
  __syncthreads();

  f32x4 acc[4][4];
  #pragma unroll
  for (int m = 0; m < 4; ++m)
    #pragma unroll
    for (int n = 0; n < 4; ++n) acc[m][n] = (f32x4){0.f, 0.f, 0.f, 0.f};

  #pragma unroll
  for (int s = 0; s < 16; ++s) {
    int u0 = s * 4 + a5;
    f16x8 A0, A1, A2, A3;
    {
      int r0 = l15,      i0 = r0 * E_DIM + ((u0 ^ swz(r0)) << 3);
      int r1 = 16 + l15, i1 = r1 * E_DIM + ((u0 ^ swz(r1)) << 3);
      int r2 = 32 + l15, i2 = r2 * E_DIM + ((u0 ^ swz(r2)) << 3);
      int r3 = 48 + l15, i3 = r3 * E_DIM + ((u0 ^ swz(r3)) << 3);
      A0 = *reinterpret_cast<const f16x8*>(&x_lds[i0]);
      A1 = *reinterpret_cast<const f16x8*>(&x_lds[i1]);
      A2 = *reinterpret_cast<const f16x8*>(&x_lds[i2]);
      A3 = *reinterpret_cast<const f16x8*>(&x_lds[i3]);
    }
    const unsigned short* wsl = wpack + ((size_t)s * 32 + nt0) * 512 + lane * 8;
    #pragma unroll
    for (int n = 0; n < 4; ++n) {
      f16x8 Bf = *reinterpret_cast<const f16x8*>(wsl + n * 512);
      acc[0][n] = __builtin_amdgcn_mfma_f32_16x16x32_f16(A0, Bf, acc[0][n], 0, 0, 0);
      acc[1][n] = __builtin_amdgcn_mfma_f32_16x16x32_f16(A1, Bf, acc[1][n], 0, 0, 0);
      acc[2][n] = __builtin_amdgcn_mfma_f32_16x16x32_f16(A2, Bf, acc[2][n], 0, 0, 0);
      acc[3][n] = __builtin_amdgcn_mfma_f32_16x16x32_f16(A3, Bf, acc[3][n], 0, 0, 0);
    }
  }

  // store fragment-major fp16, nontemporal.
  // M-tile m (rows m*16..m*16+15) -> rec block 2b + (m>>1), mt = m&1.
  #pragma unroll
  for (int m = 0; m < 4; ++m) {
    size_t bt_out = (size_t)(2 * b + (m >> 1)) * 8 + t;
    #pragma unroll
    for (int n = 0; n < 4; ++n) {
      u16x4 v;
      #pragma unroll
      for (int r = 0; r < 4; ++r) v[r] = f2h(acc[m][n][r] + bias_r[n]);
      __builtin_nontemporal_store(v,
          reinterpret_cast<u16x4*>(&prep[PRE_FRAG(bt_out, m & 1, nt0 + n) + lane * 4]));
    }
  }
}

// ---------------------------------------------------------------------------
// Phase 2: recurrence (r11 verbatim). Grid 256 (1 block/CU), 512 thr = 8 waves.
// Wave wid owns N-tiles nt0=wid*4..+3 for BOTH M-tiles.
// Weights: wave-private global_load_lds, 2-deep ring, counted vmcnt,
// ds_reads pipelined one slice ahead (A/B register sets).
// h: fp16 ping-pong (2x32KB) -> ONE barrier per step. LDS: 128 KB.
// ---------------------------------------------------------------------------
__global__ __launch_bounds__(512, 2)
void rec_kernel(const unsigned short* __restrict__ prep,
                const unsigned short* __restrict__ wpack,
                float* __restrict__ out) {
  __shared__ unsigned short h_buf[2][R_WIN * E_DIM];  // 2 x 32 KB fp16
  __shared__ unsigned short w_ring[2][8 * 2048];      // 2-deep ring, 64 KB

  const int b    = blockIdx.x;
  const int w0   = b * R_WIN;
  const int tid  = threadIdx.x;
  const int lane = tid & 63;
  const int wid  = tid >> 6;            // 0..7
  const int l15  = lane & 15;
  const int a5   = lane >> 4;
  const int nt0  = wid * 4;

  // DMA one k-slice's 4 fragments (4 contiguous KB) for this wave.
  const char* wbase = (const char*)(wpack + ((size_t)16 * 32) * 512);  // W_hh
  #define STAGE(s, p)                                                               \
    do {                                                                            \
      const char* _src = wbase + (((size_t)(s) * 32 + nt0) * 1024) + lane * 16;     \
      unsigned short* _dst = &w_ring[p][wid * 2048];                                \
      __builtin_amdgcn_global_load_lds((glb_u32*)_src, (lds_u32*)_dst, 16, 0, 0);   \
      __builtin_amdgcn_global_load_lds((glb_u32*)(_src + 1024),                     \
                                       (lds_u32*)(_dst + 512), 16, 0, 0);           \
      __builtin_amdgcn_global_load_lds((glb_u32*)(_src + 2048),                     \
                                       (lds_u32*)(_dst + 1024), 16, 0, 0);          \
      __builtin_amdgcn_global_load_lds((glb_u32*)(_src + 3072),                     \
                                       (lds_u32*)(_dst + 1536), 16, 0, 0);          \
    } while (0)

  // ---- t = 0: h[0] = tanh(PRE_0) ----
  #pragma unroll
  for (int mt = 0; mt < 2; ++mt)
    #pragma unroll
    for (int n = 0; n < 4; ++n) {
      u16x4 p = __builtin_nontemporal_load(reinterpret_cast<const u16x4*>(
          &prep[PRE_FRAG(b * 8 + 0, mt, nt0 + n) + lane * 4]));
      int ncol = (nt0 + n) * 16 + l15;
      int ub = ncol >> 3, co = ncol & 7;
      #pragma unroll
      for (int r = 0; r < 4; ++r) {
        int row = mt * 16 + a5 * 4 + r;
        int idx = row * E_DIM + ((ub ^ swz(row)) << 3) + co;
        h_buf[0][idx] = f2h(tanh_fast(h2f(p[r])));
      }
    }

  // prefetch PRE_1
  u16x4 nxt[2][4];
  #pragma unroll
  for (int mt = 0; mt < 2; ++mt)
    #pragma unroll
    for (int n = 0; n < 4; ++n)
      nxt[mt][n] = __builtin_nontemporal_load(reinterpret_cast<const u16x4*>(
          &prep[PRE_FRAG(b * 8 + 1, mt, nt0 + n) + lane * 4]));

  __syncthreads();   // h[0] visible; drains all VMEM (incl. PRE_1)

  int cur = 0;
  for (int t = 1; t < KSIZE; ++t) {
    f32x4 acc[2][4];
    #pragma unroll
    for (int mt = 0; mt < 2; ++mt)
      #pragma unroll
      for (int n = 0; n < 4; ++n) {
        #pragma unroll
        for (int r = 0; r < 4; ++r) acc[mt][n][r] = h2f(nxt[mt][n][r]);
      }

    // ---- prologue: stage slices 0,1; read slice 0 into A ----
    STAGE(0, 0);
    STAGE(1, 1);
    asm volatile("s_waitcnt vmcnt(4)" ::: "memory");   // slice 0 landed
    f16x8 Wa0, Wa1, Wa2, Wa3, Ha0, Ha1;
    f16x8 Wb0, Wb1, Wb2, Wb3, Hb0, Hb1;
    {
      const unsigned short* wsl = &w_ring[0][wid * 2048 + lane * 8];
      Wa0 = *reinterpret_cast<const f16x8*>(wsl);
      Wa1 = *reinterpret_cast<const f16x8*>(wsl + 512);
      Wa2 = *reinterpret_cast<const f16x8*>(wsl + 1024);
      Wa3 = *reinterpret_cast<const f16x8*>(wsl + 1536);
      int ia0 = l15 * E_DIM + ((a5 ^ swz(l15)) << 3);
      int ia1 = (16 + l15) * E_DIM + ((a5 ^ swz(16 + l15)) << 3);
      Ha0 = *reinterpret_cast<const f16x8*>(&h_buf[cur][ia0]);
      Ha1 = *reinterpret_cast<const f16x8*>(&h_buf[cur][ia1]);
    }

    // ---- s-loop: MFMA slice s (A regs) while reading s+1 (B regs) ----
    #pragma unroll
    for (int s = 0; s < 16; ++s) {
      // A-reads retired -> operands ready AND ring[s%2]'s reader done,
      // so STAGE(s+2) (same buffer) is WAR-safe.
      asm volatile("s_waitcnt lgkmcnt(0)" ::: "memory");
      if (s + 2 < 16) STAGE(s + 2, (s + 2) & 1);
      // counted wait: slice s+1 (issued last iter / prologue) has landed.
      if (s < 14)       asm volatile("s_waitcnt vmcnt(4)" ::: "memory");
      else if (s == 14) asm volatile("s_waitcnt vmcnt(0)" ::: "memory");
      if (s < 15) {
        const unsigned short* wsl = &w_ring[(s + 1) & 1][wid * 2048 + lane * 8];
        Wb0 = *reinterpret_cast<const f16x8*>(wsl);
        Wb1 = *reinterpret_cast<const f16x8*>(wsl + 512);
        Wb2 = *reinterpret_cast<const f16x8*>(wsl + 1024);
        Wb3 = *reinterpret_cast<const f16x8*>(wsl + 1536);
        int u0  = (s + 1) * 4 + a5;
        int ia0 = l15 * E_DIM + ((u0 ^ swz(l15)) << 3);
        int ia1 = (16 + l15) * E_DIM + ((u0 ^ swz(16 + l15)) << 3);
        Hb0 = *reinterpret_cast<const f16x8*>(&h_buf[cur][ia0]);
        Hb1 = *reinterpret_cast<const f16x8*>(&h_buf[cur][ia1]);
      }
      acc[0][0] = __builtin_amdgcn_mfma_f32_16x16x32_f16(Ha0, Wa0, acc[0][0], 0, 0, 0);
      acc[1][0] = __builtin_amdgcn_mfma_f32_16x16x32_f16(Ha1, Wa0, acc[1][0], 0, 0, 0);
      acc[0][1] = __builtin_amdgcn_mfma_f32_16x16x32_f16(Ha0, Wa1, acc[0][1], 0, 0, 0);
      acc[1][1] = __builtin_amdgcn_mfma_f32_16x16x32_f16(Ha1, Wa1, acc[1][1], 0, 0, 0);
      acc[0][2] = __builtin_amdgcn_mfma_f32_16x16x32_f16(Ha0, Wa2, acc[0][2], 0, 0, 0);
      acc[1][2] = __builtin_amdgcn_mfma_f32_16x16x32_f16(Ha1, Wa2, acc[1][2], 0, 0, 0);
      acc[0][3] = __builtin_amdgcn_mfma_f32_16x16x32_f16(Ha0, Wa3, acc[0][3], 0, 0, 0);
      acc[1][3] = __builtin_amdgcn_mfma_f32_16x16x32_f16(Ha1, Wa3, acc[1][3], 0, 0, 0);
      Wa0 = Wb0; Wa1 = Wb1; Wa2 = Wb2; Wa3 = Wb3;   // renamed by unroll
      Ha0 = Hb0; Ha1 = Hb1;
    }

    if (t == KSIZE - 1) {
      #pragma unroll
      for (int mt = 0; mt < 2; ++mt)
        #pragma unroll
        for (int n = 0; n < 4; ++n) {
          int ncol = (nt0 + n) * 16 + l15;
          #pragma unroll
          for (int r = 0; r < 4; ++r) {
            int row = mt * 16 + a5 * 4 + r;
            out[(size_t)(w0 + row) * E_DIM + ncol] = tanh_fast(acc[mt][n][r]);
          }
        }
    } else {
      // issue next step's PRE now: HBM latency hides under the epilogue;
      // the step barrier drains it (keeps the s-loop vmcnt queue clean).
      #pragma unroll
      for (int mt = 0; mt < 2; ++mt)
        #pragma unroll
        for (int n = 0; n < 4; ++n)
          nxt[mt][n] = __builtin_nontemporal_load(reinterpret_cast<const u16x4*>(
              &prep[PRE_FRAG(b * 8 + t + 1, mt, nt0 + n) + lane * 4]));

      // write h[cur^1]; waves may still read h[cur] -- different buffer.
      int nb = cur ^ 1;
      #pragma unroll
      for (int mt = 0; mt < 2; ++mt)
        #pragma unroll
        for (int n = 0; n < 4; ++n) {
          int ncol = (nt0 + n) * 16 + l15;
          int ub = ncol >> 3, co = ncol & 7;
          #pragma unroll
          for (int r = 0; r < 4; ++r) {
            int row = mt * 16 + a5 * 4 + r;
            int idx = row * E_DIM + ((ub ^ swz(row)) << 3) + co;
            h_buf[nb][idx] = f2h(tanh_fast(acc[mt][n][r]));
          }
        }
      __syncthreads();   // ONE barrier per step: h[nb] visible to all
      cur = nb;
    }
  }
  #undef STAGE
}

// ---------------------------------------------------------------------------
// Fallback (fused, fp16) for small ws_size. k-slice-major wpack.
// ---------------------------------------------------------------------------
__global__ __launch_bounds__(512, 1)
void rnnpool_fused(const float* __restrict__ x,
                   const unsigned short* __restrict__ wpack,
                   const float* __restrict__ bias,
                   float* __restrict__ out) {
  __shared__ unsigned short x_lds[R_WIN * E_DIM];
  __shared__ unsigned short h_lds[R_WIN * E_DIM];

  const int tid  = threadIdx.x;
  const int lane = tid & 63;
  const int wid  = tid >> 6;
  const int w0   = blockIdx.x * R_WIN;
  const int l15 = lane & 15;
  const int a5  = lane >> 4;
  const int nt0 = wid * 4;

  float bias_r[4];
  #pragma unroll
  for (int n = 0; n < 4; ++n) bias_r[n] = bias[(nt0 + n) * 16 + l15];

  const int srow = tid >> 4;
  const int sc4  = tid & 15;

  for (int t = 0; t < KSIZE; ++t) {
    {
      const fv4* src4 = reinterpret_cast<const fv4*>(
          x + (size_t)((w0 + srow) * KSIZE + t) * E_DIM);
      #pragma unroll
      for (int j = 0; j < 8; ++j) {
        fv4 v = src4[sc4 + 16 * j];
        int col  = (sc4 + 16 * j) * 4;
        int idx  = srow * E_DIM + (((col >> 3) ^ swz(srow)) << 3) + (col & 7);
        u16x4 u;
        u[0] = f2h(v.x); u[1] = f2h(v.y); u[2] = f2h(v.z); u[3] = f2h(v.w);
        *reinterpret_cast<u16x4*>(&x_lds[idx]) = u;
      }
    }
    __syncthreads();

    f32x4 acc[2][4];
    #pragma unroll
    for (int mt = 0; mt < 2; ++mt)
      #pragma unroll
      for (int n = 0; n < 4; ++n) acc[mt][n] = (f32x4){0.f, 0.f, 0.f, 0.f};

    #pragma unroll
    for (int s = 0; s < 16; ++s) {
      int u0 = s * 4 + a5;
      int ia = l15 * E_DIM + ((u0 ^ swz(l15)) << 3);
      f16x8 A0 = *reinterpret_cast<const f16x8*>(&x_lds[ia]);
      f16x8 A1 = *reinterpret_cast<const f16x8*>(&x_lds[ia + 16 * E_DIM]);
      const unsigned short* wsl = wpack + ((size_t)s * 32 + nt0) * 512 + lane * 8;
      #pragma unroll
      for (int n = 0; n < 4; ++n) {
        f16x8 Bf = *reinterpret_cast<const f16x8*>(wsl + n * 512);
        acc[0][n] = __builtin_amdgcn_mfma_f32_16x16x32_f16(A0, Bf, acc[0][n], 0, 0, 0);
        acc[1][n] = __builtin_amdgcn_mfma_f32_16x16x32_f16(A1, Bf, acc[1][n], 0, 0, 0);
      }
    }

    if (t > 0) {
      #pragma unroll
      for (int s = 0; s < 16; ++s) {
        int u0 = s * 4 + a5;
        int ia = l15 * E_DIM + ((u0 ^ swz(l15)) << 3);
        f16x8 H0 = *reinterpret_cast<const f16x8*>(&h_lds[ia]);
        f16x8 H1 = *reinterpret_cast<const f16x8*>(&h_lds[ia + 16 * E_DIM]);
        const unsigned short* wsl = wpack + ((size_t)(16 + s) * 32 + nt0) * 512 + lane * 8;
        #pragma unroll
        for (int n = 0; n < 4; ++n) {
          f16x8 Bf = *reinterpret_cast<const f16x8*>(wsl + n * 512);
          acc[0][n] = __builtin_amdgcn_mfma_f32_16x16x32_f16(H0, Bf, acc[0][n], 0, 0, 0);
          acc[1][n] = __builtin_amdgcn_mfma_f32_16x16x32_f16(H1, Bf, acc[1][n], 0, 0, 0);
        }
      }
    }
    __syncthreads();

    if (t == KSIZE - 1) {
      #pragma unroll
      for (int mt = 0; mt < 2; ++mt)
        #pragma unroll
        for (int n = 0; n < 4; ++n) {
          int ncol = (nt0 + n) * 16 + l15;
          #pragma unroll
          for (int r = 0; r < 4; ++r) {
            int row = mt * 16 + a5 * 4 + r;
            out[(size_t)(w0 + row) * E_DIM + ncol] = tanh_fast(acc[mt][n][r] + bias_r[n]);
          }
        }
    } else {
      #pragma unroll
      for (int mt = 0; mt < 2; ++mt)
        #pragma unroll
        for (int n = 0; n < 4; ++n) {
          int ncol = (nt0 + n) * 16 + l15;
          int ub = ncol >> 3, co = ncol & 7;
          #pragma unroll
          for (int r = 0; r < 4; ++r) {
            int row = mt * 16 + a5 * 4 + r;
            int idx = row * E_DIM + ((ub ^ swz(row)) << 3) + co;
            h_lds[idx] = f2h(tanh_fast(acc[mt][n][r] + bias_r[n]));
          }
        }
      __syncthreads();
    }
  }
}

extern "C" void kernel_launch(void* const* d_in, const int* in_sizes, int n_in,
                              void* d_out, int out_size, void* d_ws, size_t ws_size,
                              hipStream_t stream) {
  const float* x   = (const float*)d_in[0];
  const float* Wih = (const float*)d_in[1];
  const float* Whh = (const float*)d_in[2];
  const float* bih = (const float*)d_in[3];
  const float* bhh = (const float*)d_in[4];
  float* out = (float*)d_out;

  const size_t PRE_BYTES  = (size_t)33554432 * 2;      // 67.1 MB (fp16)
  const size_t WPK_BYTES  = (size_t)524288 * 2;        // 1 MB
  const size_t NEED       = PRE_BYTES + WPK_BYTES + 4096;

  if (ws_size >= NEED) {
    unsigned short* prep  = (unsigned short*)d_ws;
    unsigned short* wpack = (unsigned short*)((char*)d_ws + PRE_BYTES);
    float*          bias  = (float*)((char*)d_ws + PRE_BYTES + WPK_BYTES);
    pack_kernel<<<256, 256, 0, stream>>>(Wih, Whh, bih, bhh, wpack, bias);
    pre_kernel<<<1024, 512, 0, stream>>>(x, wpack, bias, prep);
    rec_kernel<<<NBLK, 512, 0, stream>>>(prep, wpack, out);
  } else {
    unsigned short* wpack = (unsigned short*)d_ws;
    float*          bias  = (float*)((char*)d_ws + WPK_BYTES);
    pack_kernel<<<256, 256, 0, stream>>>(Wih, Whh, bih, bhh, wpack, bias);
    rnnpool_fused<<<NBLK, 512, 0, stream>>>(x, wpack, bias, out);
  }
}